// Round 6
// baseline (789.389 us; speedup 1.0000x reference)
//
#include <hip/hip_runtime.h>

typedef unsigned long long u64;
typedef float nfloat4 __attribute__((ext_vector_type(4)));  // native vec for nontemporal ops

// ws layout:
#define OFF_A      0        // 510 floats: -0.5*||c||^2 per combo, level-major (off_L = 2^L-2)
#define OFF_DT     512      // dT[c*8+s] = w[r1[s]][c]-w[r0[s]][c]
#define OFF_V0T    1536     // v0T[c*8+s] = w[r0[s]][c]
#define OFF_BASET  2560     // baseT[(L-1)*128+c] = sum_{s<=L} w[r0[s]][c]
#define OFF_IDX_BYTES 16384         // u64 packed indices per position (65536 * 8B)
#define OFF_PART_F    135168        // float offset of partial[8][256] = (16384+65536*8)/4

__device__ __forceinline__ float warp_sum(float v) {
  #pragma unroll
  for (int off = 32; off > 0; off >>= 1) v += __shfl_down(v, off);
  return v;
}

// ---------------- Kernel A: build codebook tables ----------------------------------------
__global__ __launch_bounds__(64) void build_tables(const float* __restrict__ w,
                                                   float* __restrict__ wsf) {
  const int r0[8] = {0, 3, 4, 5, 6, 7, 8, 9};
  int e = blockIdx.x;
  int t = threadIdx.x;
  if (e < 510) {
    int ep2 = e + 2;
    int L = 31 - __clz(ep2);        // level 1..8
    int i = ep2 - (1 << L);         // combo index, b1 = MSB
    float acc = 0.f;
    #pragma unroll
    for (int half = 0; half < 2; ++half) {
      int cc = t + half * 64;
      float v = 0.f;
      for (int s = 0; s < L; ++s) {
        int b = (i >> (L - 1 - s)) & 1;
        v += w[(r0[s] + b) * 128 + cc];
      }
      acc += v * v;
    }
    acc = warp_sum(acc);
    if (t == 0) wsf[OFF_A + e] = -0.5f * acc;
  } else {
    #pragma unroll
    for (int half = 0; half < 2; ++half) {
      int cc = t + half * 64;
      float basesum = 0.f;
      #pragma unroll
      for (int s = 0; s < 8; ++s) {
        float w0 = w[r0[s] * 128 + cc];
        float w1 = w[(r0[s] + 1) * 128 + cc];
        wsf[OFF_V0T + cc * 8 + s] = w0;
        wsf[OFF_DT + cc * 8 + s] = w1 - w0;
        basesum += w0;
        wsf[OFF_BASET + s * 128 + cc] = basesum;
      }
    }
  }
}

// ---------------- Guaranteed-unroll level search (all indices compile-time) ---------------
template <int L, int I, int N>
struct SU {
  static __device__ __forceinline__ void run(const float* Al, const float* T,
                                             const float* S, float& bs, int& bi) {
    float dot;
    if constexpr (L <= 4) {
      dot = T[I << (4 - L)];
    } else {
      dot = T[I >> (L - 4)] + S[(I & ((1 << (L - 4)) - 1)) << (8 - L)];
    }
    float sc = dot + Al[I];
    if (sc > bs) { bs = sc; bi = I; }   // strict > keeps lowest index on ties
    SU<L, I + 1, N>::run(Al, T, S, bs, bi);
  }
};
template <int L, int N>
struct SU<L, N, N> {
  static __device__ __forceinline__ void run(const float*, const float*, const float*,
                                             float&, int&) {}
};

template <int L>
__device__ __forceinline__ void search_level(const float* Al_base, const float* T,
                                             const float* S, float& bestsc, int& bestidx) {
  const float* Al = Al_base + ((1 << L) - 2);
  float bs = -3.4e38f;
  int bi = 0;
  SU<L, 0, (1 << L)>::run(Al, T, S, bs, bi);
  bestsc = bs;
  bestidx = bi;
}

// ---------------- Kernel B: dots (LDS tables, batched x) + argmax + loss partials ---------
__global__ __launch_bounds__(256) void search_kernel(const float* __restrict__ in,
                                                     const float* __restrict__ tbl,
                                                     float* __restrict__ partial,
                                                     u64* __restrict__ idxp) {
  __shared__ __align__(16) float dTl[1024];
  __shared__ __align__(16) float v0l[1024];
  __shared__ float Al[512];
  __shared__ float red[4][8];

  int tid = threadIdx.x;
  for (int i = tid; i < 1024; i += 256) { dTl[i] = tbl[OFF_DT + i]; v0l[i] = tbl[OFF_V0T + i]; }
  if (tid < 255) { Al[tid] = tbl[OFF_A + tid]; Al[tid + 255] = tbl[OFF_A + tid + 255]; }
  __syncthreads();

  int pos = blockIdx.x * 256 + tid;
  int b = pos >> 12;
  int hw = pos & 4095;
  const float* xp = in + ((size_t)b << 19) + hw;   // (B,128,64,64): channel stride 4096
  const float4* dT4 = (const float4*)dTl;
  const float4* v04 = (const float4*)v0l;

  float qq[8], uu[8];
  #pragma unroll
  for (int k = 0; k < 8; ++k) { qq[k] = 0.f; uu[k] = 0.f; }
  float xx = 0.f;
  #pragma unroll
  for (int g = 0; g < 4; ++g) {
    float xv[32];
    #pragma unroll
    for (int j = 0; j < 32; ++j)                    // 32 loads in flight (MLP=32)
      xv[j] = __builtin_nontemporal_load(&xp[(size_t)(g * 32 + j) << 12]);
    #pragma unroll
    for (int j = 0; j < 32; ++j) {
      float x = xv[j];
      int c = g * 32 + j;
      float4 d0 = dT4[2 * c], d1 = dT4[2 * c + 1];  // broadcast ds_read_b128
      float4 u0 = v04[2 * c], u1 = v04[2 * c + 1];
      xx = fmaf(x, x, xx);
      qq[0] = fmaf(x, d0.x, qq[0]); qq[1] = fmaf(x, d0.y, qq[1]);
      qq[2] = fmaf(x, d0.z, qq[2]); qq[3] = fmaf(x, d0.w, qq[3]);
      qq[4] = fmaf(x, d1.x, qq[4]); qq[5] = fmaf(x, d1.y, qq[5]);
      qq[6] = fmaf(x, d1.z, qq[6]); qq[7] = fmaf(x, d1.w, qq[7]);
      uu[0] = fmaf(x, u0.x, uu[0]); uu[1] = fmaf(x, u0.y, uu[1]);
      uu[2] = fmaf(x, u0.z, uu[2]); uu[3] = fmaf(x, u0.w, uu[3]);
      uu[4] = fmaf(x, u1.x, uu[4]); uu[5] = fmaf(x, u1.y, uu[5]);
      uu[6] = fmaf(x, u1.z, uu[6]); uu[7] = fmaf(x, u1.w, uu[7]);
    }
  }

  // subset-sum tables: T over stages 1..4 (bit3<->stage1), S over stages 5..8
  float T[16], S[16];
  #pragma unroll
  for (int h = 0; h < 16; ++h) {
    float tv = 0.f, sv = 0.f;
    if (h & 8) { tv += qq[0]; sv += qq[4]; }
    if (h & 4) { tv += qq[1]; sv += qq[5]; }
    if (h & 2) { tv += qq[2]; sv += qq[6]; }
    if (h & 1) { tv += qq[3]; sv += qq[7]; }
    T[h] = tv; S[h] = sv;
  }

  float bsc[8];
  int bix[8];
  search_level<1>(Al, T, S, bsc[0], bix[0]);
  search_level<2>(Al, T, S, bsc[1], bix[1]);
  search_level<3>(Al, T, S, bsc[2], bix[2]);
  search_level<4>(Al, T, S, bsc[3], bix[3]);
  search_level<5>(Al, T, S, bsc[4], bix[4]);
  search_level<6>(Al, T, S, bsc[5], bix[5]);
  search_level<7>(Al, T, S, bsc[6], bix[6]);
  search_level<8>(Al, T, S, bsc[7], bix[7]);

  u64 pk = (u64)bix[0] | ((u64)bix[1] << 1) | ((u64)bix[2] << 3) | ((u64)bix[3] << 6) |
           ((u64)bix[4] << 10) | ((u64)bix[5] << 15) | ((u64)bix[6] << 21) |
           ((u64)bix[7] << 28);
  idxp[pos] = pk;

  // loss partials: wave reduce -> LDS -> one non-atomic store per level per block
  int wv = tid >> 6;
  float P0 = 0.f;
  #pragma unroll
  for (int l = 0; l < 8; ++l) {
    P0 += uu[l];                                   // x . base_L
    float sse = xx - 2.f * (P0 + bsc[l]);          // ||x - q||^2
    sse = warp_sum(sse);
    if ((tid & 63) == 0) red[wv][l] = sse;
  }
  __syncthreads();
  if (tid < 8)
    partial[tid * 256 + blockIdx.x] = red[0][tid] + red[1][tid] + red[2][tid] + red[3][tid];
}

// ---------------- Kernel C: reconstruct q with float4 nt-stores, final loss reduce --------
template <int LV>
__device__ __forceinline__ void write_level(const float* dTl, const float* btl,
                                            const u64* __restrict__ idxp, int pos,
                                            nfloat4* __restrict__ op) {
  constexpr int SHv = (LV == 1 ? 0 : LV == 2 ? 1 : LV == 3 ? 3 : LV == 4 ? 6 :
                       LV == 5 ? 10 : LV == 6 ? 15 : LV == 7 ? 21 : 28);
  float bf[4][LV];
  #pragma unroll
  for (int p = 0; p < 4; ++p) {
    u64 pk = idxp[pos + p];
    int idx = (int)((pk >> SHv) & ((1u << LV) - 1));
    #pragma unroll
    for (int s = 0; s < LV; ++s) bf[p][s] = (float)((idx >> (LV - 1 - s)) & 1);
  }
  #pragma unroll 2
  for (int c = 0; c < 128; ++c) {
    float bt = btl[c];
    float dv[LV];
    #pragma unroll
    for (int s = 0; s < LV; ++s) dv[s] = dTl[c * 8 + s];   // broadcast LDS
    float q0 = bt, q1 = bt, q2 = bt, q3 = bt;
    #pragma unroll
    for (int s = 0; s < LV; ++s) {
      q0 = fmaf(bf[0][s], dv[s], q0);
      q1 = fmaf(bf[1][s], dv[s], q1);
      q2 = fmaf(bf[2][s], dv[s], q2);
      q3 = fmaf(bf[3][s], dv[s], q3);
    }
    nfloat4 r = {q0, q1, q2, q3};
    __builtin_nontemporal_store(r, &op[(size_t)c << 10]);  // write-once stream
  }
}

__global__ __launch_bounds__(256) void write_kernel(const float* __restrict__ tbl,
                                                    const u64* __restrict__ idxp,
                                                    float* __restrict__ out) {
  __shared__ float dTl[1024];
  __shared__ float btl[128];
  int blk = blockIdx.x;
  int L = blk >> 6;                 // 0..7, level LV = L+1
  for (int i = threadIdx.x; i < 1024; i += 256) dTl[i] = tbl[OFF_DT + i];
  if (threadIdx.x < 128) btl[threadIdx.x] = tbl[OFF_BASET + L * 128 + threadIdx.x];
  __syncthreads();

  // deterministic final loss reduction by wave 0 of block 0 (hidden under store stream)
  if (blk == 0 && threadIdx.x < 64) {
    const float CO[8] = {1.5f, 1.2f, 1.0f, 0.9f, 0.82f, 0.69f, 0.65f, 0.56f};
    const float* partial = tbl + OFF_PART_F;
    int t = threadIdx.x;
    int l = t >> 3;
    int j = t & 7;
    float s = 0.f;
    #pragma unroll 4
    for (int k = 0; k < 32; ++k) s += partial[l * 256 + j + k * 8];
    s += __shfl_down(s, 4);
    s += __shfl_down(s, 2);
    s += __shfl_down(s, 1);
    if (j == 0)
      out[67108864ull + l] = (CO[l] + 0.4f) * s * (1.0f / 8388608.0f);
  }

  int g = (blk & 63) * 256 + threadIdx.x;   // float4-group id within level, 0..16383
  int pos = g << 2;                          // base position (4 per thread)
  int bb = pos >> 12;
  int hw = pos & 4095;
  nfloat4* op = (nfloat4*)(out + (((size_t)(L * 16 + bb)) << 19) + hw);
  switch (L) {
    case 0: write_level<1>(dTl, btl, idxp, pos, op); break;
    case 1: write_level<2>(dTl, btl, idxp, pos, op); break;
    case 2: write_level<3>(dTl, btl, idxp, pos, op); break;
    case 3: write_level<4>(dTl, btl, idxp, pos, op); break;
    case 4: write_level<5>(dTl, btl, idxp, pos, op); break;
    case 5: write_level<6>(dTl, btl, idxp, pos, op); break;
    case 6: write_level<7>(dTl, btl, idxp, pos, op); break;
    case 7: write_level<8>(dTl, btl, idxp, pos, op); break;
  }
}

extern "C" void kernel_launch(void* const* d_in, const int* in_sizes, int n_in,
                              void* d_out, int out_size, void* d_ws, size_t ws_size,
                              hipStream_t stream) {
  const float* in = (const float*)d_in[0];   // (16,128,64,64) fp32
  const float* w  = (const float*)d_in[1];   // (256,128) fp32
  float* wsf = (float*)d_ws;
  u64* idxp = (u64*)((char*)d_ws + OFF_IDX_BYTES);
  float* partial = wsf + OFF_PART_F;
  float* out = (float*)d_out;

  build_tables<<<511, 64, 0, stream>>>(w, wsf);
  search_kernel<<<256, 256, 0, stream>>>(in, wsf, partial, idxp);
  write_kernel<<<512, 256, 0, stream>>>(wsf, idxp, out);
}

// Round 7
// 360.687 us; speedup vs baseline: 2.1886x; 2.1886x over previous
//
#include <hip/hip_runtime.h>

typedef unsigned long long u64;
typedef float nfloat4 __attribute__((ext_vector_type(4)));  // native vec for nontemporal ops

// ws layout:
#define OFF_A      0        // 510 floats: -0.5*||c||^2 per combo, level-major (off_L = 2^L-2)
#define OFF_DT     512      // dT[c*8+s] = w[r1[s]][c]-w[r0[s]][c]
#define OFF_V0T    1536     // v0T[c*8+s] = w[r0[s]][c]
#define OFF_BASET  2560     // baseT[(L-1)*128+c] = sum_{s<=L} w[r0[s]][c]
#define OFF_IDX_BYTES 16384         // u64 packed indices per position (65536 * 8B)
#define OFF_PART_F    135168        // float offset of partial[8][512] = (16384+65536*8)/4

__device__ __forceinline__ float warp_sum(float v) {
  #pragma unroll
  for (int off = 32; off > 0; off >>= 1) v += __shfl_down(v, off);
  return v;
}

// ---------------- Kernel A: build codebook tables ----------------------------------------
__global__ __launch_bounds__(64) void build_tables(const float* __restrict__ w,
                                                   float* __restrict__ wsf) {
  const int r0[8] = {0, 3, 4, 5, 6, 7, 8, 9};
  int e = blockIdx.x;
  int t = threadIdx.x;
  if (e < 510) {
    int ep2 = e + 2;
    int L = 31 - __clz(ep2);        // level 1..8
    int i = ep2 - (1 << L);         // combo index, b1 = MSB
    float acc = 0.f;
    #pragma unroll
    for (int half = 0; half < 2; ++half) {
      int cc = t + half * 64;
      float v = 0.f;
      for (int s = 0; s < L; ++s) {
        int b = (i >> (L - 1 - s)) & 1;
        v += w[(r0[s] + b) * 128 + cc];
      }
      acc += v * v;
    }
    acc = warp_sum(acc);
    if (t == 0) wsf[OFF_A + e] = -0.5f * acc;
  } else {
    #pragma unroll
    for (int half = 0; half < 2; ++half) {
      int cc = t + half * 64;
      float basesum = 0.f;
      #pragma unroll
      for (int s = 0; s < 8; ++s) {
        float w0 = w[r0[s] * 128 + cc];
        float w1 = w[(r0[s] + 1) * 128 + cc];
        wsf[OFF_V0T + cc * 8 + s] = w0;
        wsf[OFF_DT + cc * 8 + s] = w1 - w0;
        basesum += w0;
        wsf[OFF_BASET + s * 128 + cc] = basesum;
      }
    }
  }
}

// ---------------- Guaranteed-unroll level search (all indices compile-time) ---------------
template <int L, int I, int N>
struct SU {
  static __device__ __forceinline__ void run(const float* Al, const float* T,
                                             const float* S, float& bs, int& bi) {
    float dot;
    if constexpr (L <= 4) {
      dot = T[I << (4 - L)];
    } else {
      dot = T[I >> (L - 4)] + S[(I & ((1 << (L - 4)) - 1)) << (8 - L)];
    }
    float sc = dot + Al[I];
    if (sc > bs) { bs = sc; bi = I; }   // strict > keeps lowest index on ties
    SU<L, I + 1, N>::run(Al, T, S, bs, bi);
  }
};
template <int L, int N>
struct SU<L, N, N> {
  static __device__ __forceinline__ void run(const float*, const float*, const float*,
                                             float&, int&) {}
};

template <int L>
__device__ __forceinline__ void search_level(const float* Al_base, const float* T,
                                             const float* S, float& bestsc, int& bestidx) {
  const float* Al = Al_base + ((1 << L) - 2);
  float bs = -3.4e38f;
  int bi = 0;
  SU<L, 0, (1 << L)>::run(Al, T, S, bs, bi);
  bestsc = bs;
  bestidx = bi;
}

// ---------------- Kernel B: dots (LDS tables, batched x) + argmax + loss partials ---------
__global__ __launch_bounds__(128) void search_kernel(const float* __restrict__ in,
                                                     const float* __restrict__ tbl,
                                                     float* __restrict__ partial,
                                                     u64* __restrict__ idxp) {
  __shared__ __align__(16) float dTl[1024];
  __shared__ __align__(16) float v0l[1024];
  __shared__ float Al[512];
  __shared__ float red[2][8];

  int tid = threadIdx.x;
  for (int i = tid; i < 1024; i += 128) { dTl[i] = tbl[OFF_DT + i]; v0l[i] = tbl[OFF_V0T + i]; }
  for (int i = tid; i < 510; i += 128) Al[i] = tbl[OFF_A + i];
  __syncthreads();

  int pos = blockIdx.x * 128 + tid;
  int b = pos >> 12;
  int hw = pos & 4095;
  const float* xp = in + ((size_t)b << 19) + hw;   // (B,128,64,64): channel stride 4096
  const float4* dT4 = (const float4*)dTl;
  const float4* v04 = (const float4*)v0l;

  float qq[8], uu[8];
  #pragma unroll
  for (int k = 0; k < 8; ++k) { qq[k] = 0.f; uu[k] = 0.f; }
  float xx = 0.f;
  #pragma unroll 1
  for (int g = 0; g < 8; ++g) {                     // NOT unrolled: bounds live registers
    float xv[16];
    #pragma unroll
    for (int j = 0; j < 16; ++j)                    // 16 loads in flight (MLP=16)
      xv[j] = xp[(size_t)(g * 16 + j) << 12];
    #pragma unroll
    for (int j = 0; j < 16; ++j) {
      float x = xv[j];
      int c = g * 16 + j;
      float4 d0 = dT4[2 * c], d1 = dT4[2 * c + 1];  // broadcast ds_read_b128
      float4 u0 = v04[2 * c], u1 = v04[2 * c + 1];
      xx = fmaf(x, x, xx);
      qq[0] = fmaf(x, d0.x, qq[0]); qq[1] = fmaf(x, d0.y, qq[1]);
      qq[2] = fmaf(x, d0.z, qq[2]); qq[3] = fmaf(x, d0.w, qq[3]);
      qq[4] = fmaf(x, d1.x, qq[4]); qq[5] = fmaf(x, d1.y, qq[5]);
      qq[6] = fmaf(x, d1.z, qq[6]); qq[7] = fmaf(x, d1.w, qq[7]);
      uu[0] = fmaf(x, u0.x, uu[0]); uu[1] = fmaf(x, u0.y, uu[1]);
      uu[2] = fmaf(x, u0.z, uu[2]); uu[3] = fmaf(x, u0.w, uu[3]);
      uu[4] = fmaf(x, u1.x, uu[4]); uu[5] = fmaf(x, u1.y, uu[5]);
      uu[6] = fmaf(x, u1.z, uu[6]); uu[7] = fmaf(x, u1.w, uu[7]);
    }
  }

  // subset-sum tables: T over stages 1..4 (bit3<->stage1), S over stages 5..8
  float T[16], S[16];
  #pragma unroll
  for (int h = 0; h < 16; ++h) {
    float tv = 0.f, sv = 0.f;
    if (h & 8) { tv += qq[0]; sv += qq[4]; }
    if (h & 4) { tv += qq[1]; sv += qq[5]; }
    if (h & 2) { tv += qq[2]; sv += qq[6]; }
    if (h & 1) { tv += qq[3]; sv += qq[7]; }
    T[h] = tv; S[h] = sv;
  }

  float bsc[8];
  int bix[8];
  search_level<1>(Al, T, S, bsc[0], bix[0]);
  search_level<2>(Al, T, S, bsc[1], bix[1]);
  search_level<3>(Al, T, S, bsc[2], bix[2]);
  search_level<4>(Al, T, S, bsc[3], bix[3]);
  search_level<5>(Al, T, S, bsc[4], bix[4]);
  search_level<6>(Al, T, S, bsc[5], bix[5]);
  search_level<7>(Al, T, S, bsc[6], bix[6]);
  search_level<8>(Al, T, S, bsc[7], bix[7]);

  u64 pk = (u64)bix[0] | ((u64)bix[1] << 1) | ((u64)bix[2] << 3) | ((u64)bix[3] << 6) |
           ((u64)bix[4] << 10) | ((u64)bix[5] << 15) | ((u64)bix[6] << 21) |
           ((u64)bix[7] << 28);
  idxp[pos] = pk;

  // loss partials: wave reduce -> LDS -> one non-atomic store per level per block
  int wv = tid >> 6;
  float P0 = 0.f;
  #pragma unroll
  for (int l = 0; l < 8; ++l) {
    P0 += uu[l];                                   // x . base_L
    float sse = xx - 2.f * (P0 + bsc[l]);          // ||x - q||^2
    sse = warp_sum(sse);
    if ((tid & 63) == 0) red[wv][l] = sse;
  }
  __syncthreads();
  if (tid < 8)
    partial[tid * 512 + blockIdx.x] = red[0][tid] + red[1][tid];
}

// ---------------- Kernel C: reconstruct q with float4 nt-stores, final loss reduce --------
template <int LV>
__device__ __forceinline__ void write_level(const float* dTl, const float* btl,
                                            const u64* __restrict__ idxp, int pos,
                                            nfloat4* __restrict__ op) {
  constexpr int SHv = (LV == 1 ? 0 : LV == 2 ? 1 : LV == 3 ? 3 : LV == 4 ? 6 :
                       LV == 5 ? 10 : LV == 6 ? 15 : LV == 7 ? 21 : 28);
  float bf[4][LV];
  #pragma unroll
  for (int p = 0; p < 4; ++p) {
    u64 pk = idxp[pos + p];
    int idx = (int)((pk >> SHv) & ((1u << LV) - 1));
    #pragma unroll
    for (int s = 0; s < LV; ++s) bf[p][s] = (float)((idx >> (LV - 1 - s)) & 1);
  }
  #pragma unroll 2
  for (int c = 0; c < 128; ++c) {
    float bt = btl[c];
    float dv[LV];
    #pragma unroll
    for (int s = 0; s < LV; ++s) dv[s] = dTl[c * 8 + s];   // broadcast LDS
    float q0 = bt, q1 = bt, q2 = bt, q3 = bt;
    #pragma unroll
    for (int s = 0; s < LV; ++s) {
      q0 = fmaf(bf[0][s], dv[s], q0);
      q1 = fmaf(bf[1][s], dv[s], q1);
      q2 = fmaf(bf[2][s], dv[s], q2);
      q3 = fmaf(bf[3][s], dv[s], q3);
    }
    nfloat4 r = {q0, q1, q2, q3};
    __builtin_nontemporal_store(r, &op[(size_t)c << 10]);  // write-once stream
  }
}

__global__ __launch_bounds__(256) void write_kernel(const float* __restrict__ tbl,
                                                    const u64* __restrict__ idxp,
                                                    float* __restrict__ out) {
  __shared__ float dTl[1024];
  __shared__ float btl[128];
  int blk = blockIdx.x;
  int L = blk >> 6;                 // 0..7, level LV = L+1
  for (int i = threadIdx.x; i < 1024; i += 256) dTl[i] = tbl[OFF_DT + i];
  if (threadIdx.x < 128) btl[threadIdx.x] = tbl[OFF_BASET + L * 128 + threadIdx.x];
  __syncthreads();

  // deterministic final loss reduction by wave 0 of block 0 (hidden under store stream)
  if (blk == 0 && threadIdx.x < 64) {
    const float CO[8] = {1.5f, 1.2f, 1.0f, 0.9f, 0.82f, 0.69f, 0.65f, 0.56f};
    const float* partial = tbl + OFF_PART_F;
    int t = threadIdx.x;
    int l = t >> 3;
    int j = t & 7;
    float s = 0.f;
    #pragma unroll 4
    for (int k = 0; k < 64; ++k) s += partial[l * 512 + j + k * 8];
    s += __shfl_down(s, 4);
    s += __shfl_down(s, 2);
    s += __shfl_down(s, 1);
    if (j == 0)
      out[67108864ull + l] = (CO[l] + 0.4f) * s * (1.0f / 8388608.0f);
  }

  int g = (blk & 63) * 256 + threadIdx.x;   // float4-group id within level, 0..16383
  int pos = g << 2;                          // base position (4 per thread)
  int bb = pos >> 12;
  int hw = pos & 4095;
  nfloat4* op = (nfloat4*)(out + (((size_t)(L * 16 + bb)) << 19) + hw);
  switch (L) {
    case 0: write_level<1>(dTl, btl, idxp, pos, op); break;
    case 1: write_level<2>(dTl, btl, idxp, pos, op); break;
    case 2: write_level<3>(dTl, btl, idxp, pos, op); break;
    case 3: write_level<4>(dTl, btl, idxp, pos, op); break;
    case 4: write_level<5>(dTl, btl, idxp, pos, op); break;
    case 5: write_level<6>(dTl, btl, idxp, pos, op); break;
    case 6: write_level<7>(dTl, btl, idxp, pos, op); break;
    case 7: write_level<8>(dTl, btl, idxp, pos, op); break;
  }
}

extern "C" void kernel_launch(void* const* d_in, const int* in_sizes, int n_in,
                              void* d_out, int out_size, void* d_ws, size_t ws_size,
                              hipStream_t stream) {
  const float* in = (const float*)d_in[0];   // (16,128,64,64) fp32
  const float* w  = (const float*)d_in[1];   // (256,128) fp32
  float* wsf = (float*)d_ws;
  u64* idxp = (u64*)((char*)d_ws + OFF_IDX_BYTES);
  float* partial = wsf + OFF_PART_F;
  float* out = (float*)d_out;

  build_tables<<<511, 64, 0, stream>>>(w, wsf);
  search_kernel<<<512, 128, 0, stream>>>(in, wsf, partial, idxp);
  write_kernel<<<512, 256, 0, stream>>>(wsf, idxp, out);
}